// Round 4
// baseline (278.510 us; speedup 1.0000x reference)
//
#include <hip/hip_runtime.h>
#include <hip/hip_bf16.h>
#include <math.h>

#define N_NODES 50000
#define N_EDGES 800000
#define NEG_SLOPE 0.2f
#define EPS_DEN 1e-9f

constexpr int SCAN_BLK = 1024;
constexpr int NB_SCAN = (N_NODES + SCAN_BLK - 1) / SCAN_BLK; // 49

__device__ inline unsigned short f2bf(float x) {
    __hip_bfloat16 h = __float2bfloat16(x);
    return *(unsigned short*)&h;
}
__device__ inline float bflo(unsigned int u) { return __uint_as_float(u << 16); }
__device__ inline float bfhi(unsigned int u) { return __uint_as_float(u & 0xffff0000u); }

// ---------------- CSR build ----------------

__global__ void count_k(const int* __restrict__ dst, int* __restrict__ deg) {
    int e = blockIdx.x * 256 + threadIdx.x;
    if (e < N_EDGES) atomicAdd(&deg[dst[e]], 1);
}

__global__ void scan1_k(const int* __restrict__ deg, int* __restrict__ off,
                        int* __restrict__ bsum) {
    __shared__ int sh[256];
    int b = blockIdx.x, t = threadIdx.x;
    int base = b * SCAN_BLK + t * 4;
    int v[4]; int s = 0;
    #pragma unroll
    for (int i = 0; i < 4; ++i) {
        int idx = base + i;
        v[i] = (idx < N_NODES) ? deg[idx] : 0;
        s += v[i];
    }
    sh[t] = s; __syncthreads();
    for (int ofs = 1; ofs < 256; ofs <<= 1) {
        int x = 0;
        if (t >= ofs) x = sh[t - ofs];
        __syncthreads();
        sh[t] += x;
        __syncthreads();
    }
    int excl = sh[t] - s;
    if (t == 255) bsum[b] = sh[255];
    int run = excl;
    #pragma unroll
    for (int i = 0; i < 4; ++i) {
        int idx = base + i;
        if (idx < N_NODES) off[idx] = run;
        run += v[i];
    }
}

// merged scan2+scan3: each 256-block spans one bsum chunk (256 | 1024 alignment)
__global__ void scan3_k(int* __restrict__ off, const int* __restrict__ bsum) {
    __shared__ int pre;
    int b = blockIdx.x;
    if (threadIdx.x == 0) {
        int s = 0;
        int nb = b >> 2;
        for (int j = 0; j < nb; ++j) s += bsum[j];
        pre = s;
    }
    __syncthreads();
    int i = b * 256 + threadIdx.x;
    if (i < N_NODES) off[i] += pre;
    if (i == 0) off[N_NODES] = N_EDGES;
}

// scatter + layer-1 edge weights (after gemm1's fused elr epilogue)
__global__ void scatter_k(const int* __restrict__ src, const int* __restrict__ dst,
                          int* __restrict__ cursor, int* __restrict__ csr,
                          int* __restrict__ perm,
                          const float* __restrict__ el1, const float* __restrict__ er1,
                          float* __restrict__ wb1) {
    int e = blockIdx.x * 256 + threadIdx.x;
    if (e >= N_EDGES) return;
    int s = src[e], d = dst[e];
    int p = atomicAdd(&cursor[d], 1);
    csr[p] = s;
    perm[e] = p;
    float4 a = *(const float4*)&el1[(size_t)s * 4];
    float4 b = *(const float4*)&er1[(size_t)d * 4];
    float4 x = make_float4(a.x + b.x, a.y + b.y, a.z + b.z, a.w + b.w);
    x.x = x.x > 0.f ? x.x : NEG_SLOPE * x.x;
    x.y = x.y > 0.f ? x.y : NEG_SLOPE * x.y;
    x.z = x.z > 0.f ? x.z : NEG_SLOPE * x.z;
    x.w = x.w > 0.f ? x.w : NEG_SLOPE * x.w;
    float4 w = make_float4(__expf(x.x), __expf(x.y), __expf(x.z), __expf(x.w));
    *(float4*)&wb1[(size_t)p * 4] = w;
}

// ---------------- GEMM1 + fused el1/er1 + bf16 feat1 out ----------------
// 64x128 tile / 256 threads, 4x8 microtile. t = ty*16+tx.
// cols: tx*4..+3 (head tx>>3) and 64+tx*4..+3 (head 2+(tx>>3)).

__global__ __launch_bounds__(256) void gemm1_k(const float* __restrict__ H,
                                               const float* __restrict__ W,
                                               const float* __restrict__ AL,
                                               const float* __restrict__ AR,
                                               unsigned short* __restrict__ Fb,
                                               float* __restrict__ el,
                                               float* __restrict__ er) {
    __shared__ float hT[16][68];   // [k][row], padded
    __shared__ float ws[16][128];  // [k][col]
    int t = threadIdx.x;
    int tx = t & 15, ty = t >> 4;
    int rowBase = blockIdx.x * 64;
    float acc[4][8] = {};

    int sr  = t >> 2;
    int sc4 = (t & 3) << 2;
    int wk  = t >> 5;
    int wj  = (t & 31) << 2;

    float4 va = make_float4(0.f, 0.f, 0.f, 0.f);
    {
        int grow = rowBase + sr;
        if (grow < N_NODES) va = *(const float4*)&H[(size_t)grow * 256 + sc4];
    }
    float4 vw0 = *(const float4*)&W[(size_t)wk * 128 + wj];
    float4 vw1 = *(const float4*)&W[(size_t)(wk + 8) * 128 + wj];

    for (int k0 = 0; k0 < 256; k0 += 16) {
        __syncthreads();
        hT[sc4 + 0][sr] = va.x; hT[sc4 + 1][sr] = va.y;
        hT[sc4 + 2][sr] = va.z; hT[sc4 + 3][sr] = va.w;
        *(float4*)&ws[wk][wj]     = vw0;
        *(float4*)&ws[wk + 8][wj] = vw1;
        __syncthreads();

        if (k0 + 16 < 256) {
            int k1 = k0 + 16;
            va = make_float4(0.f, 0.f, 0.f, 0.f);
            int grow = rowBase + sr;
            if (grow < N_NODES) va = *(const float4*)&H[(size_t)grow * 256 + k1 + sc4];
            vw0 = *(const float4*)&W[(size_t)(k1 + wk) * 128 + wj];
            vw1 = *(const float4*)&W[(size_t)(k1 + wk + 8) * 128 + wj];
        }

        #pragma unroll
        for (int k = 0; k < 16; ++k) {
            float4 a4 = *(const float4*)&hT[k][ty * 4];
            float4 b0 = *(const float4*)&ws[k][tx * 4];
            float4 b1 = *(const float4*)&ws[k][64 + tx * 4];
            float a[4] = {a4.x, a4.y, a4.z, a4.w};
            float b[8] = {b0.x, b0.y, b0.z, b0.w, b1.x, b1.y, b1.z, b1.w};
            #pragma unroll
            for (int i = 0; i < 4; ++i)
                #pragma unroll
                for (int j = 0; j < 8; ++j)
                    acc[i][j] = fmaf(a[i], b[j], acc[i][j]);
        }
    }

    // bf16 feature rows
    #pragma unroll
    for (int i = 0; i < 4; ++i) {
        int row = rowBase + ty * 4 + i;
        if (row < N_NODES) {
            ushort4 p0 = {f2bf(acc[i][0]), f2bf(acc[i][1]), f2bf(acc[i][2]), f2bf(acc[i][3])};
            ushort4 p1 = {f2bf(acc[i][4]), f2bf(acc[i][5]), f2bf(acc[i][6]), f2bf(acc[i][7])};
            *(ushort4*)&Fb[(size_t)row * 128 + tx * 4]      = p0;
            *(ushort4*)&Fb[(size_t)row * 128 + 64 + tx * 4] = p1;
        }
    }

    // fused el/er: partial dot over this thread's 8 cols, reduce over tx&7
    int hA = tx >> 3, hB = 2 + (tx >> 3);
    int ao = (tx & 7) * 4;
    float elA[4], erA[4], elB[4], erB[4];
    #pragma unroll
    for (int i = 0; i < 4; ++i) {
        float a0 = 0.f, r0 = 0.f, a1 = 0.f, r1 = 0.f;
        #pragma unroll
        for (int c = 0; c < 4; ++c) {
            a0 = fmaf(acc[i][c],     AL[hA * 32 + ao + c], a0);
            r0 = fmaf(acc[i][c],     AR[hA * 32 + ao + c], r0);
            a1 = fmaf(acc[i][4 + c], AL[hB * 32 + ao + c], a1);
            r1 = fmaf(acc[i][4 + c], AR[hB * 32 + ao + c], r1);
        }
        elA[i] = a0; erA[i] = r0; elB[i] = a1; erB[i] = r1;
    }
    #pragma unroll
    for (int m = 1; m <= 4; m <<= 1) {
        #pragma unroll
        for (int i = 0; i < 4; ++i) {
            elA[i] += __shfl_xor(elA[i], m, 64);
            erA[i] += __shfl_xor(erA[i], m, 64);
            elB[i] += __shfl_xor(elB[i], m, 64);
            erB[i] += __shfl_xor(erB[i], m, 64);
        }
    }
    if ((tx & 7) == 0) {
        #pragma unroll
        for (int i = 0; i < 4; ++i) {
            int row = rowBase + ty * 4 + i;
            if (row < N_NODES) {
                el[(size_t)row * 4 + hA] = elA[i];
                er[(size_t)row * 4 + hA] = erA[i];
                el[(size_t)row * 4 + hB] = elB[i];
                er[(size_t)row * 4 + hB] = erB[i];
            }
        }
    }
}

// ---------------- agg1: wave-per-node, 4 edge slots x 16 lanes (bf16x8) ----------------

__global__ __launch_bounds__(256) void agg1_k(const unsigned short* __restrict__ Fb,
                                              const int* __restrict__ off,
                                              const int* __restrict__ csr,
                                              const float* __restrict__ wb1,
                                              const float* __restrict__ b1,
                                              const float* __restrict__ W2,
                                              const float* __restrict__ al2,
                                              const float* __restrict__ ar2,
                                              unsigned short* __restrict__ feat2b,
                                              float* __restrict__ el2,
                                              float* __restrict__ er2) {
    __shared__ float h1row[4][128];
    int wid = threadIdx.x >> 6;
    int n = blockIdx.x * 4 + wid;
    if (n >= N_NODES) return;
    int t = threadIdx.x & 63;
    int g = t >> 4;        // edge slot 0..3
    int l = t & 15;        // dim group: dims 8l..8l+7
    int hh = l >> 2;       // head
    int e0 = off[n], e1 = off[n + 1];

    float a0 = 0.f, a1 = 0.f, a2 = 0.f, a3 = 0.f, a4 = 0.f, a5 = 0.f, a6 = 0.f, a7 = 0.f;
    float dsum = 0.f;
    for (int e = e0 + g; e < e1; e += 4) {
        int s = csr[e];
        float w = wb1[(size_t)e * 4 + hh];
        uint4 u = *(const uint4*)&Fb[(size_t)s * 128 + l * 8];
        a0 = fmaf(w, bflo(u.x), a0); a1 = fmaf(w, bfhi(u.x), a1);
        a2 = fmaf(w, bflo(u.y), a2); a3 = fmaf(w, bfhi(u.y), a3);
        a4 = fmaf(w, bflo(u.z), a4); a5 = fmaf(w, bfhi(u.z), a5);
        a6 = fmaf(w, bflo(u.w), a6); a7 = fmaf(w, bfhi(u.w), a7);
        dsum += w;
    }
    #pragma unroll
    for (int m = 16; m <= 32; m <<= 1) {
        a0 += __shfl_xor(a0, m, 64); a1 += __shfl_xor(a1, m, 64);
        a2 += __shfl_xor(a2, m, 64); a3 += __shfl_xor(a3, m, 64);
        a4 += __shfl_xor(a4, m, 64); a5 += __shfl_xor(a5, m, 64);
        a6 += __shfl_xor(a6, m, 64); a7 += __shfl_xor(a7, m, 64);
        dsum += __shfl_xor(dsum, m, 64);
    }

    float inv = 1.f / (dsum + EPS_DEN);
    float o[8] = {a0, a1, a2, a3, a4, a5, a6, a7};
    #pragma unroll
    for (int j = 0; j < 8; ++j) {
        float v = fmaf(o[j], inv, b1[l * 8 + j]);
        o[j] = v > 0.f ? v : expm1f(v);
    }
    if (g == 0) {
        *(float4*)&h1row[wid][l * 8]     = make_float4(o[0], o[1], o[2], o[3]);
        *(float4*)&h1row[wid][l * 8 + 4] = make_float4(o[4], o[5], o[6], o[7]);
    }
    // wave-coherent LDS RAW within the same wave

    int j = t & 31, halfk = t >> 5;
    float part = 0.f;
    int kb = halfk << 6;
    #pragma unroll 8
    for (int k = 0; k < 64; ++k)
        part = fmaf(h1row[wid][kb + k], W2[(size_t)(kb + k) * 32 + j], part);
    part += __shfl_xor(part, 32, 64);

    if (t < 32) {
        feat2b[(size_t)n * 32 + j] = f2bf(part);
        float sl = part * al2[j];
        float sr = part * ar2[j];
        #pragma unroll
        for (int m = 16; m >= 1; m >>= 1) {
            sl += __shfl_xor(sl, m, 64);
            sr += __shfl_xor(sr, m, 64);
        }
        if (j == 0) { el2[n] = sl; er2[n] = sr; }
    }
}

// ---------------- layer-2 edge weights ----------------

__global__ void w2_k(const int* __restrict__ src, const int* __restrict__ dst,
                     const int* __restrict__ perm, const float* __restrict__ el2,
                     const float* __restrict__ er2, float* __restrict__ w2buf) {
    int e = blockIdx.x * 256 + threadIdx.x;
    if (e >= N_EDGES) return;
    float x = el2[src[e]] + er2[dst[e]];
    x = x > 0.f ? x : NEG_SLOPE * x;
    w2buf[perm[e]] = __expf(x);
}

// ---------------- agg2: wave-per-node, 16 edge slots x 4 lanes (bf16x8) ----------------

__global__ __launch_bounds__(256) void agg2_k(const unsigned short* __restrict__ F2b,
                                              const int* __restrict__ off,
                                              const int* __restrict__ csr,
                                              const float* __restrict__ w2,
                                              const float* __restrict__ b2,
                                              float* __restrict__ out) {
    int wid = threadIdx.x >> 6;
    int n = blockIdx.x * 4 + wid;
    if (n >= N_NODES) return;
    int t = threadIdx.x & 63;
    int g = t >> 2, l = t & 3;   // dims 8l..8l+7
    int e0 = off[n], e1 = off[n + 1];

    float a0 = 0.f, a1 = 0.f, a2 = 0.f, a3 = 0.f, a4 = 0.f, a5 = 0.f, a6 = 0.f, a7 = 0.f;
    float dsum = 0.f;
    for (int e = e0 + g; e < e1; e += 16) {
        int s = csr[e];
        float w = w2[e];
        uint4 u = *(const uint4*)&F2b[(size_t)s * 32 + l * 8];
        a0 = fmaf(w, bflo(u.x), a0); a1 = fmaf(w, bfhi(u.x), a1);
        a2 = fmaf(w, bflo(u.y), a2); a3 = fmaf(w, bfhi(u.y), a3);
        a4 = fmaf(w, bflo(u.z), a4); a5 = fmaf(w, bfhi(u.z), a5);
        a6 = fmaf(w, bflo(u.w), a6); a7 = fmaf(w, bfhi(u.w), a7);
        dsum += w;
    }
    #pragma unroll
    for (int m = 4; m <= 32; m <<= 1) {
        a0 += __shfl_xor(a0, m, 64); a1 += __shfl_xor(a1, m, 64);
        a2 += __shfl_xor(a2, m, 64); a3 += __shfl_xor(a3, m, 64);
        a4 += __shfl_xor(a4, m, 64); a5 += __shfl_xor(a5, m, 64);
        a6 += __shfl_xor(a6, m, 64); a7 += __shfl_xor(a7, m, 64);
        dsum += __shfl_xor(dsum, m, 64);
    }
    if (t < 4) {
        float inv = 1.f / (dsum + EPS_DEN);
        float4 r0, r1;
        r0.x = fmaf(a0, inv, b2[l * 8 + 0]);
        r0.y = fmaf(a1, inv, b2[l * 8 + 1]);
        r0.z = fmaf(a2, inv, b2[l * 8 + 2]);
        r0.w = fmaf(a3, inv, b2[l * 8 + 3]);
        r1.x = fmaf(a4, inv, b2[l * 8 + 4]);
        r1.y = fmaf(a5, inv, b2[l * 8 + 5]);
        r1.z = fmaf(a6, inv, b2[l * 8 + 6]);
        r1.w = fmaf(a7, inv, b2[l * 8 + 7]);
        *(float4*)&out[(size_t)n * 32 + l * 8]     = r0;
        *(float4*)&out[(size_t)n * 32 + l * 8 + 4] = r1;
    }
}

// ---------------- launch ----------------

extern "C" void kernel_launch(void* const* d_in, const int* in_sizes, int n_in,
                              void* d_out, int out_size, void* d_ws, size_t ws_size,
                              hipStream_t stream) {
    const float* h   = (const float*)d_in[0];
    const float* W1  = (const float*)d_in[1];
    const float* al1 = (const float*)d_in[2];
    const float* ar1 = (const float*)d_in[3];
    const float* b1  = (const float*)d_in[4];
    const float* W2  = (const float*)d_in[5];
    const float* al2 = (const float*)d_in[6];
    const float* ar2 = (const float*)d_in[7];
    const float* b2  = (const float*)d_in[8];
    const int* src   = (const int*)d_in[9];
    const int* dst   = (const int*)d_in[10];
    float* out = (float*)d_out;

    char* wsb = (char*)d_ws;
    size_t o = 0;
    auto alloc = [&](size_t bytes) {
        void* p = wsb + o;
        o += (bytes + 255) & ~(size_t)255;
        return p;
    };
    int* deg     = (int*)alloc((size_t)N_NODES * 4);
    int* off     = (int*)alloc((size_t)(N_NODES + 1) * 4);
    int* cursor  = (int*)alloc((size_t)N_NODES * 4);
    int* csr     = (int*)alloc((size_t)N_EDGES * 4);
    int* perm    = (int*)alloc((size_t)N_EDGES * 4);
    int* bsum    = (int*)alloc((size_t)NB_SCAN * 4);
    unsigned short* feat1b = (unsigned short*)alloc((size_t)N_NODES * 128 * 2);
    float* el1   = (float*)alloc((size_t)N_NODES * 4 * 4);
    float* er1   = (float*)alloc((size_t)N_NODES * 4 * 4);
    float* wb1   = (float*)alloc((size_t)N_EDGES * 4 * 4);
    unsigned short* feat2b = (unsigned short*)alloc((size_t)N_NODES * 32 * 2);
    float* el2   = (float*)alloc((size_t)N_NODES * 4);
    float* er2   = (float*)alloc((size_t)N_NODES * 4);
    float* w2buf = wb1;  // reuse: wb1 dead after agg1

    hipMemsetAsync(deg, 0, (size_t)N_NODES * 4, stream);
    count_k<<<(N_EDGES + 255) / 256, 256, 0, stream>>>(dst, deg);
    scan1_k<<<NB_SCAN, 256, 0, stream>>>(deg, off, bsum);
    scan3_k<<<(N_NODES + 255) / 256, 256, 0, stream>>>(off, bsum);
    hipMemcpyAsync(cursor, off, (size_t)N_NODES * 4, hipMemcpyDeviceToDevice, stream);
    gemm1_k<<<(N_NODES + 63) / 64, 256, 0, stream>>>(h, W1, al1, ar1, feat1b, el1, er1);
    scatter_k<<<(N_EDGES + 255) / 256, 256, 0, stream>>>(src, dst, cursor, csr, perm,
                                                         el1, er1, wb1);
    agg1_k<<<(N_NODES + 3) / 4, 256, 0, stream>>>(feat1b, off, csr, wb1, b1, W2,
                                                  al2, ar2, feat2b, el2, er2);
    w2_k<<<(N_EDGES + 255) / 256, 256, 0, stream>>>(src, dst, perm, el2, er2, w2buf);
    agg2_k<<<(N_NODES + 3) / 4, 256, 0, stream>>>(feat2b, off, csr, w2buf, b2, out);
}